// Round 7
// baseline (9892.273 us; speedup 1.0000x reference)
//
#include <hip/hip_runtime.h>
#include <hip/hip_bf16.h>
#include <hip/hip_fp16.h>

// Problem constants
#define BB   128
#define TT   256
#define EE   300
#define KP0  320             // E padded to mult of 64
#define HH   512
#define GG   2048            // 4*H gates
#define NC   11
#define MM   (BB*TT)         // 32768
#define START_TAG 9
#define STOP_TAG  10
#define NEGV (-100000.0f)

typedef _Float16 h2_t __attribute__((ext_vector_type(2)));
typedef _Float16 h4_t __attribute__((ext_vector_type(4)));
typedef _Float16 h8_t __attribute__((ext_vector_type(8)));
typedef float    f4_t __attribute__((ext_vector_type(4)));

__device__ __forceinline__ float sigf(float x) { return 1.0f / (1.0f + __expf(-x)); }
__device__ __forceinline__ float tanhf_fast(float x) {
    x = fminf(fmaxf(x, -15.f), 15.f);
    float e = __expf(2.0f * x);
    return (e - 1.0f) / (e + 1.0f);
}

// ---------------- init: zero flags/claims + loss slot ----------------
__global__ __launch_bounds__(256) void init_kernel(float* out, int* flags) {
    int t = threadIdx.x;
    if (t == 0) out[MM] = 0.0f;
    for (int i = t; i < 2048; i += 256) flags[i] = 0;
}

// ---------------- f32 -> f16 convert with K-pad (4-wide) ----------------
__global__ __launch_bounds__(256) void conv_pad_kernel(const float* __restrict__ W,
                                                       _Float16* __restrict__ O,
                                                       int K, int Kp4, int total4) {
    int idx = blockIdx.x * 256 + threadIdx.x;
    if (idx >= total4) return;
    int r = idx / Kp4, c4 = idx % Kp4, c = c4 * 4;
    h4_t v;
    if (c < K) {
        float4 f = *(const float4*)(W + (size_t)r * K + c);
        v[0] = (_Float16)f.x; v[1] = (_Float16)f.y; v[2] = (_Float16)f.z; v[3] = (_Float16)f.w;
    } else {
        v[0] = v[1] = v[2] = v[3] = (_Float16)0.0f;
    }
    *(h4_t*)(O + (size_t)r * (Kp4 * 4) + c) = v;
}

// ---------------- embedding gather -> f16 padded ----------------
__global__ __launch_bounds__(256) void embed16_kernel(const int* __restrict__ tok,
                                                      const float* __restrict__ emb,
                                                      _Float16* __restrict__ x0,
                                                      int total4) {
    int idx = blockIdx.x * 256 + threadIdx.x;
    if (idx >= total4) return;
    int m = idx / (KP0 / 4), c4 = idx % (KP0 / 4), c = c4 * 4;
    h4_t v;
    if (c < EE) {
        float4 f = *(const float4*)(emb + (size_t)tok[m] * EE + c);
        v[0] = (_Float16)f.x; v[1] = (_Float16)f.y; v[2] = (_Float16)f.z; v[3] = (_Float16)f.w;
    } else {
        v[0] = v[1] = v[2] = v[3] = (_Float16)0.0f;
    }
    *(h4_t*)(x0 + (size_t)m * KP0 + c) = v;
}

// ---------------- MFMA GEMM: C[m,n] = sum_k A[m,k]*W[n,k] + b1[n]+b2[n] ----------------
#define LDA 72
__global__ __launch_bounds__(256) void gemm_bt_kernel(const _Float16* __restrict__ A,
                                                      const _Float16* __restrict__ Wf,
                                                      const float* __restrict__ b1,
                                                      const float* __restrict__ b2,
                                                      _Float16* __restrict__ C,
                                                      int Kp) {
    __shared__ __align__(16) char smem[36864];
    _Float16* As = (_Float16*)smem;             // [128][72]
    _Float16* Bs = (_Float16*)(smem + 18432);   // [128][72]
    const int tid = threadIdx.x;
    const int m0 = blockIdx.y * 128, n0 = blockIdx.x * 128;
    const int wv = tid >> 6, lane = tid & 63;
    const int wm = wv & 1, wn = wv >> 1;
    const int col = lane & 15, quad = lane >> 4;

    f4_t acc[4][4];
#pragma unroll
    for (int i = 0; i < 4; ++i)
#pragma unroll
        for (int j = 0; j < 4; ++j) acc[i][j] = (f4_t){0.f, 0.f, 0.f, 0.f};

    for (int k0 = 0; k0 < Kp; k0 += 64) {
#pragma unroll
        for (int cch = 0; cch < 4; ++cch) {
            int id = cch * 256 + tid;
            int row = id >> 3, cc = id & 7;
            h8_t va = *(const h8_t*)(A + (size_t)(m0 + row) * Kp + k0 + cc * 8);
            h8_t vb = *(const h8_t*)(Wf + (size_t)(n0 + row) * Kp + k0 + cc * 8);
            *(h8_t*)(As + row * LDA + cc * 8) = va;
            *(h8_t*)(Bs + row * LDA + cc * 8) = vb;
        }
        __syncthreads();
#pragma unroll
        for (int kk = 0; kk < 2; ++kk) {
            h8_t af[4], bf[4];
#pragma unroll
            for (int i = 0; i < 4; ++i) {
                af[i] = *(const h8_t*)(As + (wm * 64 + i * 16 + col) * LDA + kk * 32 + quad * 8);
                bf[i] = *(const h8_t*)(Bs + (wn * 64 + i * 16 + col) * LDA + kk * 32 + quad * 8);
            }
#pragma unroll
            for (int mi = 0; mi < 4; ++mi)
#pragma unroll
                for (int ni = 0; ni < 4; ++ni)
                    acc[mi][ni] = __builtin_amdgcn_mfma_f32_16x16x32_f16(af[mi], bf[ni], acc[mi][ni], 0, 0, 0);
        }
        __syncthreads();
    }

    _Float16* Ct = (_Float16*)smem;   // [128][136]
#pragma unroll
    for (int ni = 0; ni < 4; ++ni) {
        int n = n0 + wn * 64 + ni * 16 + col;
        float bias = b1[n] + b2[n];
#pragma unroll
        for (int mi = 0; mi < 4; ++mi) {
#pragma unroll
            for (int r = 0; r < 4; ++r) {
                int mrow = wm * 64 + mi * 16 + quad * 4 + r;
                Ct[mrow * 136 + wn * 64 + ni * 16 + col] = (_Float16)(acc[mi][ni][r] + bias);
            }
        }
    }
    __syncthreads();
    {
        int row = tid >> 1, half = tid & 1;
#pragma unroll
        for (int cc2 = 0; cc2 < 8; ++cc2) {
            h8_t v = *(const h8_t*)(Ct + row * 136 + half * 64 + cc2 * 8);
            *(h8_t*)(C + (size_t)(m0 + row) * GG + n0 + half * 64 + cc2 * 8) = v;
        }
    }
}

// ============ XCD-local weight-stationary persistent LSTM recurrence ============
// Launch 256 WGs (1/CU @ 130KB LDS). Each WG reads its XCD id (s_getreg
// HW_REG_XCC_ID, runtime role assignment => correctness never depends on
// placement), claims a slot via system-scope atomic; first 16 per XCD serve
// group = xcd = (dir,bg); rest exit. Each WG holds FULL W_hh slice for 32
// hidden units (4 gates x 32 rows x 512 k f16 = 128KB LDS). h exchanged via
// sc0-only (XCD-L2-local) stores/loads; epoch flags via sc0+sc1 (MALL) for
// cross-replay freshness.
__global__ __launch_bounds__(256, 1) void lstm_rec4_kernel(
        const _Float16* __restrict__ gx_f, const _Float16* __restrict__ gx_r,
        const float* __restrict__ whh_f, const float* __restrict__ whh_r,
        const int* __restrict__ seqlen, int c0, int nbg,
        _Float16* __restrict__ hs, _Float16* __restrict__ hbuf, int* __restrict__ region) {
    extern __shared__ _Float16 Wlds[];                 // 128KB W + 2KB stage
    _Float16* hstage = Wlds + 65536;                   // [32 rows][32 cols]
    __shared__ int claim_s;

    const int tid = threadIdx.x;
    if (tid == 0) {
        int xcd;
        asm volatile("s_getreg_b32 %0, hwreg(HW_REG_XCC_ID)" : "=s"(xcd));
        xcd &= 7;
        int slot = __hip_atomic_fetch_add(region + 128 + xcd, 1,
                                          __ATOMIC_RELAXED, __HIP_MEMORY_SCOPE_SYSTEM);
        claim_s = (xcd << 8) | (slot < 255 ? slot : 255);
    }
    __syncthreads();
    const int grp = claim_s >> 8;       // = xcd
    const int gs  = claim_s & 255;
    const int ngrp = 2 * nbg;
    if (grp >= ngrp || gs >= 16) return;

    const int bg = grp % nbg;
    const int dir = grp / nbg;
    const _Float16* gx = dir ? gx_r : gx_f;
    const float* W = dir ? whh_r : whh_f;
    int* myFlags = region + grp * 16;
    _Float16* hb = hbuf + (size_t)grp * 2 * 16384;

    const int wv = tid >> 6, lane = tid & 63;
    const int mt = wv & 1;                   // m-tile (batch rows mt*16..+15)
    const int p  = wv >> 1;                  // hidden half-slice p*16..+15
    const int col = lane & 15, quad = lane >> 4;

    // ---- pack W slice (hidden gs*32..+31, all 4 gates) into LDS ----
    // layout: [p(2)][pr(2)][sub(2)][kc(16)][lane(64)] x h8
    for (int e = tid; e < 8192; e += 256) {
        int ln = e & 63;
        int kc = (e >> 6) & 15;
        int sub = (e >> 10) & 1;
        int pr  = (e >> 11) & 1;
        int pp  = (e >> 12) & 1;
        int n = ln & 15;
        int g = pr * 2 + (n >> 3);
        int R = g * 512 + gs * 32 + pp * 16 + sub * 8 + (n & 7);
        int k = kc * 32 + (ln >> 4) * 8;
        const float4* src = (const float4*)(W + (size_t)R * 512 + k);
        float4 f0 = src[0], f1 = src[1];
        h8_t v;
        v[0] = (_Float16)f0.x; v[1] = (_Float16)f0.y; v[2] = (_Float16)f0.z; v[3] = (_Float16)f0.w;
        v[4] = (_Float16)f1.x; v[5] = (_Float16)f1.y; v[6] = (_Float16)f1.z; v[7] = (_Float16)f1.w;
        *(h8_t*)(Wlds + (size_t)e * 8) = v;
    }
    __syncthreads();

    const int maxsl = seqlen[c0 + bg * 32];
    int sl_r[4];
#pragma unroll
    for (int r = 0; r < 4; ++r) sl_r[r] = seqlen[c0 + bg * 32 + mt * 16 + quad * 4 + r];

    const int hi = col >> 3;
    int jsub[2];
#pragma unroll
    for (int sub = 0; sub < 2; ++sub) jsub[sub] = gs * 32 + p * 16 + sub * 8 + (col & 7);

    // ---- prefetch gx for step 0 (plain cached loads) ----
    _Float16 pg0[4][2], pg1[4][2];
#pragma unroll
    for (int r = 0; r < 4; ++r)
#pragma unroll
        for (int sub = 0; sub < 2; ++sub) {
            pg0[r][sub] = (_Float16)0.0f; pg1[r][sub] = (_Float16)0.0f;
            if (0 < sl_r[r]) {
                int tm = dir ? (sl_r[r] - 1) : 0;
                int b_loc = bg * 32 + mt * 16 + quad * 4 + r;
                size_t base = ((size_t)(b_loc * TT + tm)) * GG;
                pg0[r][sub] = gx[base + hi * 512 + jsub[sub]];
                pg1[r][sub] = gx[base + 1024 + hi * 512 + jsub[sub]];
            }
        }

    // ---- publish h_{-1}=0 into buf1 (sc0: lands dirty-local in this XCD L2) ----
    if (tid < 256) {
        int m = tid >> 3, q = tid & 7;
        unsigned long long z = 0ull;
        const _Float16* dst = hb + 16384 + m * 512 + gs * 32 + q * 4;
        asm volatile("global_store_dwordx2 %0, %1, off sc0" :: "v"(dst), "v"(z) : "memory");
    }
    asm volatile("s_waitcnt vmcnt(0)" ::: "memory");
    __syncthreads();
    if (tid == 0) {
        int one = 1;
        asm volatile("global_store_dword %0, %1, off sc0 sc1" :: "v"(myFlags + gs), "v"(one) : "memory");
    }

    float cst[4][2] = {{0.f,0.f},{0.f,0.f},{0.f,0.f},{0.f,0.f}};
    float hst[4][2] = {{0.f,0.f},{0.f,0.f},{0.f,0.f},{0.f,0.f}};

    for (int s = 0; s < maxsl; ++s) {
        // ---- wait: all 16 WGs published h_{s-1} ----
        if (tid < 16) {
            const int* fp = myFlags + tid;
            int v, it = 0;
            for (;;) {
                asm volatile("global_load_dword %0, %1, off sc0 sc1\n\ts_waitcnt vmcnt(0)"
                             : "=v"(v) : "v"(fp) : "memory");
                if (v >= s + 1) break;
                if (it < 3) __builtin_amdgcn_s_sleep(1);
                else        __builtin_amdgcn_s_sleep(4);
                ++it;
            }
        }
        __syncthreads();

        const _Float16* hrd = hb + ((s + 1) & 1) * 16384;
        _Float16* hwr = hb + (s & 1) * 16384;

        // ---- load A fragments from XCD-local L2 (sc0) ----
        h8_t a[16];
        const _Float16* ap = hrd + (mt * 16 + col) * 512 + quad * 8;
#pragma unroll
        for (int kc = 0; kc < 16; ++kc)
            asm volatile("global_load_dwordx4 %0, %1, off sc0"
                         : "=v"(a[kc]) : "v"(ap + kc * 32));
        asm volatile("s_waitcnt vmcnt(0)" ::: "memory");

        // ---- 64 MFMA: gates[m=32(x2 waves)][n=64 of this wave] ----
        f4_t acc[2][2];   // [pr(if|go)][sub]
#pragma unroll
        for (int pr = 0; pr < 2; ++pr)
#pragma unroll
            for (int sub = 0; sub < 2; ++sub) acc[pr][sub] = (f4_t){0.f,0.f,0.f,0.f};
#pragma unroll
        for (int kc = 0; kc < 16; ++kc) {
#pragma unroll
            for (int pr = 0; pr < 2; ++pr)
#pragma unroll
                for (int sub = 0; sub < 2; ++sub) {
                    h8_t b = *(const h8_t*)(Wlds +
                        ((size_t)(p * 4096 + pr * 2048 + sub * 1024 + kc * 64 + lane)) * 8);
                    acc[pr][sub] = __builtin_amdgcn_mfma_f32_16x16x32_f16(a[kc], b, acc[pr][sub], 0, 0, 0);
                }
        }

        // ---- gates + state update; stage h in LDS ----
#pragma unroll
        for (int r = 0; r < 4; ++r) {
            const bool valid = (s < sl_r[r]);
#pragma unroll
            for (int sub = 0; sub < 2; ++sub) {
                float a0 = acc[0][sub][r] + (float)pg0[r][sub];
                float a1 = acc[1][sub][r] + (float)pg1[r][sub];
                float x0v = __shfl_xor(a0, 8);
                float x1v = __shfl_xor(a1, 8);
                float gi = hi ? x0v : a0;
                float gf = hi ? a0 : x0v;
                float gg2 = hi ? x1v : a1;
                float go = hi ? a1 : x1v;
                if (valid) {
                    float cn = sigf(gf) * cst[r][sub] + sigf(gi) * tanhf_fast(gg2);
                    cst[r][sub] = cn;
                    hst[r][sub] = sigf(go) * tanhf_fast(cn);
                }
                if (!hi)
                    hstage[(mt * 16 + quad * 4 + r) * 32 + p * 16 + sub * 8 + (col & 7)] =
                        (_Float16)hst[r][sub];
            }
        }
        __syncthreads();

        // ---- publish h_s slice (sc0, XCD-local), clean drain ----
        if (tid < 256) {
            int m = tid >> 3, q = tid & 7;
            unsigned long long v = *(const unsigned long long*)(hstage + m * 32 + q * 4);
            const _Float16* dst = hwr + m * 512 + gs * 32 + q * 4;
            asm volatile("global_store_dwordx2 %0, %1, off sc0" :: "v"(dst), "v"(v) : "memory");
        }
        asm volatile("s_waitcnt vmcnt(0)" ::: "memory");
        __syncthreads();
        if (tid == 0) {
            int fv = s + 2;
            asm volatile("global_store_dword %0, %1, off sc0 sc1" :: "v"(myFlags + gs), "v"(fv) : "memory");
        }

        // ---- post-flag shadow work (overlaps next poll) ----
#pragma unroll
        for (int r = 0; r < 4; ++r) {
            const bool valid = (s < sl_r[r]);
            if (valid && !hi) {
                int b_loc = bg * 32 + mt * 16 + quad * 4 + r;
                int tm = dir ? (sl_r[r] - 1 - s) : s;
                size_t ob = ((size_t)(b_loc * TT + tm) << 10) + (dir << 9);
#pragma unroll
                for (int sub = 0; sub < 2; ++sub)
                    hs[ob + jsub[sub]] = (_Float16)hst[r][sub];
            }
        }
        {
            int sn = s + 1;
#pragma unroll
            for (int r = 0; r < 4; ++r)
#pragma unroll
                for (int sub = 0; sub < 2; ++sub) {
                    pg0[r][sub] = (_Float16)0.0f; pg1[r][sub] = (_Float16)0.0f;
                    if (sn < sl_r[r]) {
                        int tm = dir ? (sl_r[r] - 1 - sn) : sn;
                        int b_loc = bg * 32 + mt * 16 + quad * 4 + r;
                        size_t base = ((size_t)(b_loc * TT + tm)) * GG;
                        pg0[r][sub] = gx[base + hi * 512 + jsub[sub]];
                        pg1[r][sub] = gx[base + 1024 + hi * 512 + jsub[sub]];
                    }
                }
        }
    }
}

// ---------------- emissions ----------------
__global__ __launch_bounds__(256) void emis_kernel(const _Float16* __restrict__ hs,
                                                   const float* __restrict__ fc_w,
                                                   const float* __restrict__ fc_b,
                                                   float* __restrict__ emis, int n) {
    int idx = blockIdx.x * 256 + threadIdx.x;
    if (idx >= n) return;
    int m = idx / NC, cc = idx % NC;
    const h8_t* a = (const h8_t*)(hs + (size_t)m * 1024);
    const float4* w = (const float4*)(fc_w + (size_t)cc * 1024);
    float s = 0.f;
#pragma unroll 4
    for (int k = 0; k < 128; ++k) {
        h8_t x = a[k];
        float4 y0 = w[2 * k], y1 = w[2 * k + 1];
        s += (float)x[0] * y0.x + (float)x[1] * y0.y + (float)x[2] * y0.z + (float)x[3] * y0.w;
        s += (float)x[4] * y1.x + (float)x[5] * y1.y + (float)x[6] * y1.z + (float)x[7] * y1.w;
    }
    emis[idx] = s + fc_b[cc];
}

// ---------------- CRF: Viterbi + NLL forward ----------------
__global__ __launch_bounds__(64) void crf_kernel(const float* __restrict__ emis,
                                                 const int* __restrict__ seq_len,
                                                 const int* __restrict__ tags,
                                                 const float* __restrict__ trans,
                                                 unsigned char* __restrict__ bt,
                                                 float* __restrict__ out, int c0) {
    const int b_loc = blockIdx.x;
    const int b = c0 + b_loc;
    const int lane = threadIdx.x;
    __shared__ float tr[NC * NC];
    for (int i = lane; i < NC * NC; i += 64) tr[i] = trans[i];
    __syncthreads();
    const int sl = seq_len[b];
    const bool act = lane < NC;
    const int jj = act ? lane : 0;

    float vs = 0.0f;
    float ns = NEGV;

    for (int t = 0; t < sl; ++t) {
        float ej = act ? emis[(size_t)(b_loc * TT + t) * NC + lane] : 0.0f;
        float vmax = -1e30f, nmax = -1e30f;
        int varg = 0;
        float nsave[NC];
#pragma unroll
        for (int i = 0; i < NC; ++i) {
            float vi = __shfl(vs, i);
            float ni = __shfl(ns, i);
            float tij = tr[i * NC + jj];
            float cv = vi + tij;
            if (cv > vmax) { vmax = cv; varg = i; }
            float cn = ni + tij;
            nsave[i] = cn;
            if (cn > nmax) nmax = cn;
        }
        float ssum = 0.f;
#pragma unroll
        for (int i = 0; i < NC; ++i) ssum += expf(nsave[i] - nmax);
        if (act) {
            vs = vmax + ej;
            ns = nmax + logf(ssum) + ej;
            bt[(size_t)(b_loc * TT + t) * NC + lane] = (unsigned char)varg;
        }
    }

    float finv = act ? vs + tr[lane * NC + STOP_TAG] : -1e30f;
    float finn = act ? ns + tr[lane * NC + STOP_TAG] : -1e30f;
    float vbest = -1e30f, fmax = -1e30f;
    int barg = 0;
#pragma unroll
    for (int j = 0; j < NC; ++j) {
        float v = __shfl(finv, j);
        if (v > vbest) { vbest = v; barg = j; }
        float n = __shfl(finn, j);
        if (n > fmax) fmax = n;
    }
    float fsum = 0.f;
#pragma unroll
    for (int j = 0; j < NC; ++j) fsum += expf(__shfl(finn, j) - fmax);
    float fwd = fmax + logf(fsum);

    float gsum = 0.f;
    for (int t = lane; t < sl; t += 64) {
        int tg = tags[b * TT + t];
        int pv = (t == 0) ? START_TAG : tags[b * TT + t - 1];
        gsum += emis[(size_t)(b_loc * TT + t) * NC + tg] + tr[pv * NC + tg];
    }
#pragma unroll
    for (int off = 32; off > 0; off >>= 1) gsum += __shfl_down(gsum, off);

    if (lane == 0) {
        float gold = gsum + tr[tags[b * TT + sl - 1] * NC + STOP_TAG];
        atomicAdd(out + MM, (fwd - gold) * (1.0f / (float)BB));
        int cur = barg;
        for (int l = sl - 1; l >= 0; --l) {
            out[b * TT + l] = (float)cur;
            if (l >= 1) cur = (int)bt[(size_t)(b_loc * TT + l) * NC + cur];
        }
    }
    for (int l = sl + lane; l < TT; l += 64) out[b * TT + l] = 0.0f;
}

// ---------------- launch ----------------
extern "C" void kernel_launch(void* const* d_in, const int* in_sizes, int n_in,
                              void* d_out, int out_size, void* d_ws, size_t ws_size,
                              hipStream_t stream) {
    (void)in_sizes; (void)n_in; (void)out_size;
    const int* tokens = (const int*)d_in[0];
    const int* seqlen = (const int*)d_in[1];
    const int* tags = (const int*)d_in[3];
    const float* emb = (const float*)d_in[4];
    const float* w_ih_l0  = (const float*)d_in[5];
    const float* w_hh_l0  = (const float*)d_in[6];
    const float* b_ih_l0  = (const float*)d_in[7];
    const float* b_hh_l0  = (const float*)d_in[8];
    const float* w_ih_l0r = (const float*)d_in[9];
    const float* w_hh_l0r = (const float*)d_in[10];
    const float* b_ih_l0r = (const float*)d_in[11];
    const float* b_hh_l0r = (const float*)d_in[12];
    const float* w_ih_l1  = (const float*)d_in[13];
    const float* w_hh_l1  = (const float*)d_in[14];
    const float* b_ih_l1  = (const float*)d_in[15];
    const float* b_hh_l1  = (const float*)d_in[16];
    const float* w_ih_l1r = (const float*)d_in[17];
    const float* w_hh_l1r = (const float*)d_in[18];
    const float* b_ih_l1r = (const float*)d_in[19];
    const float* b_hh_l1r = (const float*)d_in[20];
    const float* fc_w  = (const float*)d_in[21];
    const float* fc_b  = (const float*)d_in[22];
    const float* trans = (const float*)d_in[23];

    // opt-in to >64KB dynamic LDS for the recurrence kernel (host-side, capture-safe)
    static bool attr_set = false;
    if (!attr_set) {
        hipFuncSetAttribute((const void*)lstm_rec4_kernel,
                            hipFuncAttributeMaxDynamicSharedMemorySize, 133120);
        attr_set = true;
    }

    // ---- workspace layout ----
    const size_t per_b = 2097152u + 524288u + 163840u + 11264u + 2816u;  // 2,799,360
    const size_t fixed = 524288u + 8192u + 2u * 1310720u + 2u * 4194304u;
    int Bc = 128;
    while (Bc > 32 && fixed + per_b * (size_t)Bc > ws_size) Bc >>= 1;

    char* ws = (char*)d_ws;
    _Float16* hbuf = (_Float16*)ws;               // 8 grp x 2 x 32x512 f16
    int* flags = (int*)(ws + 524288u);            // 2048 ints: 8 regions x 192
    _Float16* w0f = (_Float16*)(ws + 532480u);
    _Float16* w0r = (_Float16*)(ws + 532480u + 1310720u);
    _Float16* w1f = (_Float16*)(ws + 532480u + 2u * 1310720u);
    _Float16* w1r = (_Float16*)(ws + 532480u + 2u * 1310720u + 4194304u);
    char* p = ws + fixed;
    _Float16* gxf   = (_Float16*)p;   p += (size_t)Bc * 1048576u;
    _Float16* gxr   = (_Float16*)p;   p += (size_t)Bc * 1048576u;
    _Float16* hs    = (_Float16*)p;   p += (size_t)Bc * 524288u;
    _Float16* x0f16 = (_Float16*)p;   p += (size_t)Bc * 163840u;
    float* emis     = (float*)p;      p += (size_t)Bc * 11264u;
    unsigned char* bt = (unsigned char*)p;
    float* out = (float*)d_out;   // pred as floats [0,MM), loss at [MM]

    init_kernel<<<1, 256, 0, stream>>>(out, flags);
    conv_pad_kernel<<<(2048 * 80 + 255) / 256, 256, 0, stream>>>(w_ih_l0,  w0f, EE, 80, 2048 * 80);
    conv_pad_kernel<<<(2048 * 80 + 255) / 256, 256, 0, stream>>>(w_ih_l0r, w0r, EE, 80, 2048 * 80);
    conv_pad_kernel<<<(2048 * 256 + 255) / 256, 256, 0, stream>>>(w_ih_l1,  w1f, 1024, 256, 2048 * 256);
    conv_pad_kernel<<<(2048 * 256 + 255) / 256, 256, 0, stream>>>(w_ih_l1r, w1r, 1024, 256, 2048 * 256);

    const int nbg = Bc / 32;
    const int nchunk = BB / Bc;
    for (int cidx = 0; cidx < nchunk; ++cidx) {
        const int c0 = cidx * Bc;
        const int Mc = Bc * TT;
        dim3 gdim(GG / 128, Mc / 128);
        int* rg_l0 = flags + (cidx * 2 + 0) * 192;
        int* rg_l1 = flags + (cidx * 2 + 1) * 192;

        embed16_kernel<<<(Mc * 80 + 255) / 256, 256, 0, stream>>>(tokens + c0 * TT, emb, x0f16, Mc * 80);
        gemm_bt_kernel<<<gdim, 256, 0, stream>>>(x0f16, w0f, b_ih_l0,  b_hh_l0,  gxf, KP0);
        gemm_bt_kernel<<<gdim, 256, 0, stream>>>(x0f16, w0r, b_ih_l0r, b_hh_l0r, gxr, KP0);
        lstm_rec4_kernel<<<256, 256, 133120, stream>>>(
            gxf, gxr, w_hh_l0, w_hh_l0r, seqlen, c0, nbg, hs, hbuf, rg_l0);
        gemm_bt_kernel<<<gdim, 256, 0, stream>>>(hs, w1f, b_ih_l1,  b_hh_l1,  gxf, 1024);
        gemm_bt_kernel<<<gdim, 256, 0, stream>>>(hs, w1r, b_ih_l1r, b_hh_l1r, gxr, 1024);
        lstm_rec4_kernel<<<256, 256, 133120, stream>>>(
            gxf, gxr, w_hh_l1, w_hh_l1r, seqlen, c0, nbg, hs, hbuf, rg_l1);
        emis_kernel<<<(Mc * NC + 255) / 256, 256, 0, stream>>>(hs, fc_w, fc_b, emis, Mc * NC);
        crf_kernel<<<Bc, 64, 0, stream>>>(emis, seqlen, tags, trans, bt, out, c0);
    }
}